// Round 7
// baseline (51.938 us; speedup 1.0000x reference)
//
#include <hip/hip_runtime.h>
#include <hip/hip_bf16.h>
#include <math.h>

// Problem constants (match reference)
#define B 8
#define L 2048
#define H 2048
#define NA 8
#define NEG_INF (-1e30f)

#define XT 64          // column tiles per b (32 cols each)
#define COLS 32
#define HSPLIT 4
#define HQ (H / HSPLIT)   // 512 rows per block

__device__ __forceinline__ float sigf(float t) {
    // 1/(1+exp(-t)) with raw v_rcp_f32 (no IEEE div sequence). |rel err| ~1e-7.
    return __builtin_amdgcn_rcpf(1.0f + __expf(-t));
}

// Kernel 1: partial Wy. Wyp[b,hz,x] = sum_{h in quarter hz} y[b,h]*weight[h,x]*sig(wa[a_b,h,x])
//           (+ bias[x]*sig(ba[a_b,x]) folded into the hz==0 partial)
// grid (XT, B, HSPLIT) = 2048 blocks (~8/CU, 32 waves/CU), 256 threads.
// Thread (hg = t>>3, c4 = t&7) strides 32 rows over its quarter; LDS tree reduce.
// No atomics/fences; wa re-reads across equal actions dedup in the 256MiB L3.
__global__ __launch_bounds__(256) void k_wy(
    const float* __restrict__ y, const int* __restrict__ actions,
    const float* __restrict__ weight, const float* __restrict__ wa,
    const float* __restrict__ bias, const float* __restrict__ ba,
    float* __restrict__ Wyp)
{
    const int b   = blockIdx.y;
    const int hz  = blockIdx.z;          // h-quarter 0..3
    const int x0  = blockIdx.x * COLS;
    const int a   = actions[b];
    const int c4  = threadIdx.x & 7;     // float4 column within block
    const int hg  = threadIdx.x >> 3;    // 0..31
    const int h0  = hz * HQ;

    __shared__ float ylds[HQ];           // 2 KB (one 256-thread float2 pass)
    *(float2*)(ylds + threadIdx.x * 2) =
        *(const float2*)(y + (size_t)b * H + h0 + threadIdx.x * 2);
    __syncthreads();

    const float* __restrict__ wp = weight + (size_t)h0 * H + x0 + c4 * 4;
    const float* __restrict__ ap = wa + ((size_t)a * H + h0) * H + x0 + c4 * 4;

    float4 acc = make_float4(0.f, 0.f, 0.f, 0.f);
    #pragma unroll 8
    for (int h = hg; h < HQ; h += 32) {            // 16 iterations
        const float  yv = ylds[h];
        const float4 w4 = *(const float4*)(wp + (size_t)h * H);
        const float4 a4 = *(const float4*)(ap + (size_t)h * H);
        acc.x += yv * w4.x * sigf(a4.x);
        acc.y += yv * w4.y * sigf(a4.y);
        acc.z += yv * w4.z * sigf(a4.z);
        acc.w += yv * w4.w * sigf(a4.w);
    }

    __shared__ float4 red[32][8];        // 4 KB
    red[hg][c4] = acc;
    __syncthreads();
    #pragma unroll
    for (int s = 16; s; s >>= 1) {
        if (hg < s) {
            const float4 v = red[hg + s][c4];
            acc.x += v.x; acc.y += v.y; acc.z += v.z; acc.w += v.w;
            red[hg][c4] = acc;
        }
        __syncthreads();
    }

    if (hg == 0) {
        if (hz == 0) {                   // bias term exactly once per (b,x)
            const float4 bi  = *(const float4*)(bias + x0 + c4 * 4);
            const float4 bav = *(const float4*)(ba + (size_t)a * H + x0 + c4 * 4);
            acc.x += bi.x * sigf(bav.x);
            acc.y += bi.y * sigf(bav.y);
            acc.z += bi.z * sigf(bav.z);
            acc.w += bi.w * sigf(bav.w);
        }
        *(float4*)(Wyp + ((size_t)(b * HSPLIT + hz)) * H + x0 + c4 * 4) = acc;
    }
}

// Kernel 2: xWy[b,l] = sum_h x[b,l,h]*Wy[b,h] (+mask). One wave per row.
// Staging sums the HSPLIT Wyp slots into LDS (256 KB scratch, L2-resident).
// grid: B*L/4 = 4096 blocks x 256 threads (4 waves/block; block never straddles b).
__global__ __launch_bounds__(256) void k_xwy(
    const float* __restrict__ x, const float* __restrict__ Wyp,
    const unsigned char* __restrict__ mask, float* __restrict__ xWy)
{
    const int wave = threadIdx.x >> 6;
    const int lane = threadIdx.x & 63;
    const int row  = blockIdx.x * 4 + wave;        // 0..B*L-1
    const int b    = (blockIdx.x * 4) >> 11;       // uniform per block

    __shared__ float wlds[H];                      // 8 KB
    for (int i = threadIdx.x * 4; i < H; i += 1024) {
        float4 s = make_float4(0.f, 0.f, 0.f, 0.f);
        #pragma unroll
        for (int hz = 0; hz < HSPLIT; ++hz) {
            const float4 v = *(const float4*)(Wyp + ((size_t)(b * HSPLIT + hz)) * H + i);
            s.x += v.x; s.y += v.y; s.z += v.z; s.w += v.w;
        }
        *(float4*)(wlds + i) = s;
    }
    __syncthreads();

    const float* __restrict__ xb = x + (size_t)row * H;

    float acc = 0.f;
    #pragma unroll
    for (int j = 0; j < H / 256; ++j) {            // 8 iters
        const int off = j * 256 + lane * 4;
        const float4 xv = *(const float4*)(xb + off);
        const float4 wv = *(const float4*)(wlds + off);
        acc += xv.x * wv.x + xv.y * wv.y + xv.z * wv.z + xv.w * wv.w;
    }
    #pragma unroll
    for (int s = 32; s; s >>= 1) acc += __shfl_xor(acc, s, 64);
    if (lane == 0) xWy[row] = mask[row] ? NEG_INF : acc;
}

// Kernel 3: softmax over L per batch row. grid: B blocks x 256 threads (8 elems/thread).
__global__ __launch_bounds__(256) void k_softmax(
    const float* __restrict__ xWy, float* __restrict__ out)
{
    const int b    = blockIdx.x;
    const int tid  = threadIdx.x;
    const int wave = tid >> 6;
    const int lane = tid & 63;
    const float* __restrict__ v = xWy + (size_t)b * L;

    float vals[L / 256];
    float m = -INFINITY;
    #pragma unroll
    for (int j = 0; j < L / 256; ++j) {
        vals[j] = v[tid + j * 256];
        m = fmaxf(m, vals[j]);
    }
    #pragma unroll
    for (int s = 32; s; s >>= 1) m = fmaxf(m, __shfl_xor(m, s, 64));

    __shared__ float redm[4];
    if (lane == 0) redm[wave] = m;
    __syncthreads();
    m = fmaxf(fmaxf(redm[0], redm[1]), fmaxf(redm[2], redm[3]));

    float sum = 0.f;
    #pragma unroll
    for (int j = 0; j < L / 256; ++j) {
        vals[j] = __expf(vals[j] - m);
        sum += vals[j];
    }
    #pragma unroll
    for (int s = 32; s; s >>= 1) sum += __shfl_xor(sum, s, 64);

    __shared__ float reds[4];
    if (lane == 0) reds[wave] = sum;
    __syncthreads();
    sum = reds[0] + reds[1] + reds[2] + reds[3];

    const float inv = 1.0f / sum;
    #pragma unroll
    for (int j = 0; j < L / 256; ++j)
        out[(size_t)b * L + tid + j * 256] = vals[j] * inv;
}

extern "C" void kernel_launch(void* const* d_in, const int* in_sizes, int n_in,
                              void* d_out, int out_size, void* d_ws, size_t ws_size,
                              hipStream_t stream) {
    const float*         x       = (const float*)d_in[0];
    const float*         y       = (const float*)d_in[1];
    const unsigned char* mask    = (const unsigned char*)d_in[2];
    const int*           actions = (const int*)d_in[3];
    const float*         weight  = (const float*)d_in[4];
    const float*         bias    = (const float*)d_in[5];
    const float*         wa      = (const float*)d_in[6];
    const float*         ba      = (const float*)d_in[7];
    float*               out     = (float*)d_out;

    float* ws  = (float*)d_ws;
    float* Wyp = ws;                                // B*HSPLIT*H floats = 256 KB
    float* xWy = Wyp + (size_t)B * HSPLIT * H;      // B*L floats

    dim3 g1(XT, B, HSPLIT);
    k_wy<<<g1, 256, 0, stream>>>(y, actions, weight, wa, bias, ba, Wyp);
    k_xwy<<<B * L / 4, 256, 0, stream>>>(x, Wyp, mask, xWy);
    k_softmax<<<B, 256, 0, stream>>>(xWy, out);
}

// Round 8
// 49.150 us; speedup vs baseline: 1.0567x; 1.0567x over previous
//
#include <hip/hip_runtime.h>
#include <hip/hip_bf16.h>
#include <math.h>

// Problem constants (match reference)
#define B 8
#define L 2048
#define H 2048
#define NA 8
#define NEG_INF (-1e30f)

#define XT 64          // column tiles per b (32 cols each)
#define COLS 32
#define HHALF (H / 2)  // 1024

__device__ __forceinline__ float sigf(float t) {
    // 1/(1+exp(-t)) with raw v_rcp_f32 (no IEEE div sequence). |rel err| ~1e-7.
    return __builtin_amdgcn_rcpf(1.0f + __expf(-t));
}

// Kernel 1: partial Wy. Wyp[b,hz,x] = sum_{h in half hz} y[b,h]*weight[h,x]*sig(wa[a_b,h,x])
//           (+ bias[x]*sig(ba[a_b,x]) folded into the hz==0 partial)
// grid (XT, B, 2) = 1024 blocks (4/CU, 16 waves/CU), 256 threads.  [proven round-6 config;
// HSPLIT=4 regressed (round 7): doubled per-block fixed cost + doubled k_xwy staging]
// Thread (hg = t>>3, c4 = t&7) strides 32 rows over its half; LDS tree reduce.
// No atomics/fences; wa re-reads across equal actions dedup in the 256MiB L3
// (same xt+b-offset blocks land on the same XCD: ids differ by multiples of 64).
__global__ __launch_bounds__(256) void k_wy(
    const float* __restrict__ y, const int* __restrict__ actions,
    const float* __restrict__ weight, const float* __restrict__ wa,
    const float* __restrict__ bias, const float* __restrict__ ba,
    float* __restrict__ Wyp)
{
    const int b   = blockIdx.y;
    const int hz  = blockIdx.z;          // h-half 0/1
    const int x0  = blockIdx.x * COLS;
    const int a   = actions[b];
    const int c4  = threadIdx.x & 7;     // float4 column within block
    const int hg  = threadIdx.x >> 3;    // 0..31
    const int h0  = hz * HHALF;

    __shared__ float ylds[HHALF];        // 4 KB (one 256-thread float4 pass)
    *(float4*)(ylds + threadIdx.x * 4) =
        *(const float4*)(y + (size_t)b * H + h0 + threadIdx.x * 4);
    __syncthreads();

    const float* __restrict__ wp = weight + (size_t)h0 * H + x0 + c4 * 4;
    const float* __restrict__ ap = wa + ((size_t)a * H + h0) * H + x0 + c4 * 4;

    float4 acc = make_float4(0.f, 0.f, 0.f, 0.f);
    #pragma unroll 8
    for (int h = hg; h < HHALF; h += 32) {         // 32 iterations
        const float  yv = ylds[h];
        const float4 w4 = *(const float4*)(wp + (size_t)h * H);
        const float4 a4 = *(const float4*)(ap + (size_t)h * H);
        acc.x += yv * w4.x * sigf(a4.x);
        acc.y += yv * w4.y * sigf(a4.y);
        acc.z += yv * w4.z * sigf(a4.z);
        acc.w += yv * w4.w * sigf(a4.w);
    }

    __shared__ float4 red[32][8];        // 4 KB
    red[hg][c4] = acc;
    __syncthreads();
    #pragma unroll
    for (int s = 16; s; s >>= 1) {
        if (hg < s) {
            const float4 v = red[hg + s][c4];
            acc.x += v.x; acc.y += v.y; acc.z += v.z; acc.w += v.w;
            red[hg][c4] = acc;
        }
        __syncthreads();
    }

    if (hg == 0) {
        if (hz == 0) {                   // bias term exactly once per (b,x)
            const float4 bi  = *(const float4*)(bias + x0 + c4 * 4);
            const float4 bav = *(const float4*)(ba + (size_t)a * H + x0 + c4 * 4);
            acc.x += bi.x * sigf(bav.x);
            acc.y += bi.y * sigf(bav.y);
            acc.z += bi.z * sigf(bav.z);
            acc.w += bi.w * sigf(bav.w);
        }
        *(float4*)(Wyp + ((size_t)(b * 2 + hz)) * H + x0 + c4 * 4) = acc;
    }
}

// Kernel 2: xWy[b,l] = sum_h x[b,l,h]*Wy[b,h] (+mask). One wave per row (proven),
// but 512-thread blocks: 8 waves/block, one Wyp->LDS staging per 8 rows
// (halves staging L2 traffic + per-block fixed cost vs 256-thread blocks).
// grid: B*L/8 = 2048 blocks; block never straddles b (256 blocks per b).
__global__ __launch_bounds__(512) void k_xwy(
    const float* __restrict__ x, const float* __restrict__ Wyp,
    const unsigned char* __restrict__ mask, float* __restrict__ xWy)
{
    const int wave = threadIdx.x >> 6;             // 0..7
    const int lane = threadIdx.x & 63;
    const int row  = blockIdx.x * 8 + wave;        // 0..B*L-1
    const int b    = (blockIdx.x * 8) >> 11;       // uniform per block

    __shared__ float wlds[H];                      // 8 KB
    {
        const int i = threadIdx.x * 4;             // exactly one float4 per thread
        const float4 v0 = *(const float4*)(Wyp + ((size_t)(b * 2 + 0)) * H + i);
        const float4 v1 = *(const float4*)(Wyp + ((size_t)(b * 2 + 1)) * H + i);
        float4 s; s.x = v0.x + v1.x; s.y = v0.y + v1.y;
        s.z = v0.z + v1.z; s.w = v0.w + v1.w;
        *(float4*)(wlds + i) = s;
    }
    __syncthreads();

    const float* __restrict__ xb = x + (size_t)row * H;

    float acc = 0.f;
    #pragma unroll
    for (int j = 0; j < H / 256; ++j) {            // 8 iters
        const int off = j * 256 + lane * 4;
        const float4 xv = *(const float4*)(xb + off);
        const float4 wv = *(const float4*)(wlds + off);
        acc += xv.x * wv.x + xv.y * wv.y + xv.z * wv.z + xv.w * wv.w;
    }
    #pragma unroll
    for (int s = 32; s; s >>= 1) acc += __shfl_xor(acc, s, 64);
    if (lane == 0) xWy[row] = mask[row] ? NEG_INF : acc;
}

// Kernel 3: softmax over L per batch row. grid: B blocks x 256 threads (8 elems/thread).
__global__ __launch_bounds__(256) void k_softmax(
    const float* __restrict__ xWy, float* __restrict__ out)
{
    const int b    = blockIdx.x;
    const int tid  = threadIdx.x;
    const int wave = tid >> 6;
    const int lane = tid & 63;
    const float* __restrict__ v = xWy + (size_t)b * L;

    float vals[L / 256];
    float m = -INFINITY;
    #pragma unroll
    for (int j = 0; j < L / 256; ++j) {
        vals[j] = v[tid + j * 256];
        m = fmaxf(m, vals[j]);
    }
    #pragma unroll
    for (int s = 32; s; s >>= 1) m = fmaxf(m, __shfl_xor(m, s, 64));

    __shared__ float redm[4];
    if (lane == 0) redm[wave] = m;
    __syncthreads();
    m = fmaxf(fmaxf(redm[0], redm[1]), fmaxf(redm[2], redm[3]));

    float sum = 0.f;
    #pragma unroll
    for (int j = 0; j < L / 256; ++j) {
        vals[j] = __expf(vals[j] - m);
        sum += vals[j];
    }
    #pragma unroll
    for (int s = 32; s; s >>= 1) sum += __shfl_xor(sum, s, 64);

    __shared__ float reds[4];
    if (lane == 0) reds[wave] = sum;
    __syncthreads();
    sum = reds[0] + reds[1] + reds[2] + reds[3];

    const float inv = 1.0f / sum;
    #pragma unroll
    for (int j = 0; j < L / 256; ++j)
        out[(size_t)b * L + tid + j * 256] = vals[j] * inv;
}

extern "C" void kernel_launch(void* const* d_in, const int* in_sizes, int n_in,
                              void* d_out, int out_size, void* d_ws, size_t ws_size,
                              hipStream_t stream) {
    const float*         x       = (const float*)d_in[0];
    const float*         y       = (const float*)d_in[1];
    const unsigned char* mask    = (const unsigned char*)d_in[2];
    const int*           actions = (const int*)d_in[3];
    const float*         weight  = (const float*)d_in[4];
    const float*         bias    = (const float*)d_in[5];
    const float*         wa      = (const float*)d_in[6];
    const float*         ba      = (const float*)d_in[7];
    float*               out     = (float*)d_out;

    float* ws  = (float*)d_ws;
    float* Wyp = ws;                           // B*2*H floats = 128 KB
    float* xWy = Wyp + (size_t)B * 2 * H;      // B*L floats

    dim3 g1(XT, B, 2);
    k_wy<<<g1, 256, 0, stream>>>(y, actions, weight, wa, bias, ba, Wyp);
    k_xwy<<<B * L / 8, 512, 0, stream>>>(x, Wyp, mask, xWy);
    k_softmax<<<B, 256, 0, stream>>>(xWy, out);
}

// Round 9
// 48.678 us; speedup vs baseline: 1.0670x; 1.0097x over previous
//
#include <hip/hip_runtime.h>
#include <hip/hip_bf16.h>
#include <math.h>

// Problem constants (match reference)
#define B 8
#define L 2048
#define H 2048
#define NA 8
#define NEG_INF (-1e30f)

#define XT 64             // column tiles (32 cols each)
#define COLS 32
#define HSPLIT 4
#define HQ (H / HSPLIT)   // 512 rows per block

__device__ __forceinline__ float sigf(float t) {
    // 1/(1+exp(-t)) with raw v_rcp_f32 (no IEEE div sequence). |rel err| ~1e-7.
    return __builtin_amdgcn_rcpf(1.0f + __expf(-t));
}

// Kernel 1: paired-batch partial Wy.
//   Wyp[b,hz,x] = sum_{h in quarter hz} y[b,h]*weight[h,x]*sig(wa[a_b,h,x])
//   (+ bias[x]*sig(ba[a_b,x]) folded into hz==0)
// Each block processes TWO batches (b, b+4) for one (x-tile, h-quarter): the
// weight tile is loaded ONCE and applied to both -> weight logical traffic
// halves (128->64 MiB). Static 2-stream inner loop, no branches (round-4's
// 8-way predicated version was latency-bound; 2-way static is the safe form).
// grid (XT, B/2, HSPLIT) = 1024 blocks (4/CU, 16 waves/CU as proven in r6), 256 thr.
__global__ __launch_bounds__(256, 4) void k_wy(
    const float* __restrict__ y, const int* __restrict__ actions,
    const float* __restrict__ weight, const float* __restrict__ wa,
    const float* __restrict__ bias, const float* __restrict__ ba,
    float* __restrict__ Wyp)
{
    const int b0  = blockIdx.y;          // 0..3
    const int b1  = b0 + 4;
    const int hz  = blockIdx.z;          // h-quarter 0..3
    const int x0  = blockIdx.x * COLS;
    const int a0  = actions[b0];
    const int a1  = actions[b1];
    const int c4  = threadIdx.x & 7;     // float4 column within tile
    const int hg  = threadIdx.x >> 3;    // 0..31
    const int h0  = hz * HQ;

    __shared__ float ylds[2][HQ];        // 4 KB
    *(float2*)(&ylds[0][threadIdx.x * 2]) =
        *(const float2*)(y + (size_t)b0 * H + h0 + threadIdx.x * 2);
    *(float2*)(&ylds[1][threadIdx.x * 2]) =
        *(const float2*)(y + (size_t)b1 * H + h0 + threadIdx.x * 2);
    __syncthreads();

    const float* __restrict__ wp  = weight + (size_t)h0 * H + x0 + c4 * 4;
    const float* __restrict__ ap0 = wa + ((size_t)a0 * H + h0) * H + x0 + c4 * 4;
    const float* __restrict__ ap1 = wa + ((size_t)a1 * H + h0) * H + x0 + c4 * 4;

    float4 acc0 = make_float4(0.f, 0.f, 0.f, 0.f);
    float4 acc1 = make_float4(0.f, 0.f, 0.f, 0.f);
    #pragma unroll 4
    for (int h = hg; h < HQ; h += 32) {            // 16 iterations
        const float  yv0 = ylds[0][h];
        const float  yv1 = ylds[1][h];
        const float4 w4  = *(const float4*)(wp  + (size_t)h * H);
        const float4 a40 = *(const float4*)(ap0 + (size_t)h * H);
        const float4 a41 = *(const float4*)(ap1 + (size_t)h * H);
        acc0.x += yv0 * w4.x * sigf(a40.x);
        acc0.y += yv0 * w4.y * sigf(a40.y);
        acc0.z += yv0 * w4.z * sigf(a40.z);
        acc0.w += yv0 * w4.w * sigf(a40.w);
        acc1.x += yv1 * w4.x * sigf(a41.x);
        acc1.y += yv1 * w4.y * sigf(a41.y);
        acc1.z += yv1 * w4.z * sigf(a41.z);
        acc1.w += yv1 * w4.w * sigf(a41.w);
    }

    __shared__ float4 red[2][32][8];     // 8 KB
    red[0][hg][c4] = acc0;
    red[1][hg][c4] = acc1;
    __syncthreads();
    #pragma unroll
    for (int s = 16; s; s >>= 1) {
        if (hg < s) {
            const float4 v0 = red[0][hg + s][c4];
            const float4 v1 = red[1][hg + s][c4];
            acc0.x += v0.x; acc0.y += v0.y; acc0.z += v0.z; acc0.w += v0.w;
            acc1.x += v1.x; acc1.y += v1.y; acc1.z += v1.z; acc1.w += v1.w;
            red[0][hg][c4] = acc0;
            red[1][hg][c4] = acc1;
        }
        __syncthreads();
    }

    if (hg == 0) {
        if (hz == 0) {                   // bias term exactly once per (b,x)
            const float4 bi   = *(const float4*)(bias + x0 + c4 * 4);
            const float4 bav0 = *(const float4*)(ba + (size_t)a0 * H + x0 + c4 * 4);
            const float4 bav1 = *(const float4*)(ba + (size_t)a1 * H + x0 + c4 * 4);
            acc0.x += bi.x * sigf(bav0.x);
            acc0.y += bi.y * sigf(bav0.y);
            acc0.z += bi.z * sigf(bav0.z);
            acc0.w += bi.w * sigf(bav0.w);
            acc1.x += bi.x * sigf(bav1.x);
            acc1.y += bi.y * sigf(bav1.y);
            acc1.z += bi.z * sigf(bav1.z);
            acc1.w += bi.w * sigf(bav1.w);
        }
        *(float4*)(Wyp + ((size_t)(b0 * HSPLIT + hz)) * H + x0 + c4 * 4) = acc0;
        *(float4*)(Wyp + ((size_t)(b1 * HSPLIT + hz)) * H + x0 + c4 * 4) = acc1;
    }
}

// Kernel 2: xWy[b,l] = sum_h x[b,l,h]*Wy[b,h] (+mask). One wave per row,
// 512-thread blocks (8 waves): one Wyp->LDS staging (4 slots summed) per 8 rows.
// grid: B*L/8 = 2048 blocks; block never straddles b (256 blocks per b).
__global__ __launch_bounds__(512) void k_xwy(
    const float* __restrict__ x, const float* __restrict__ Wyp,
    const unsigned char* __restrict__ mask, float* __restrict__ xWy)
{
    const int wave = threadIdx.x >> 6;             // 0..7
    const int lane = threadIdx.x & 63;
    const int row  = blockIdx.x * 8 + wave;        // 0..B*L-1
    const int b    = (blockIdx.x * 8) >> 11;       // uniform per block

    __shared__ float wlds[H];                      // 8 KB
    {
        const int i = threadIdx.x * 4;             // exactly one float4 per thread
        float4 s = make_float4(0.f, 0.f, 0.f, 0.f);
        #pragma unroll
        for (int hz = 0; hz < HSPLIT; ++hz) {
            const float4 v = *(const float4*)(Wyp + ((size_t)(b * HSPLIT + hz)) * H + i);
            s.x += v.x; s.y += v.y; s.z += v.z; s.w += v.w;
        }
        *(float4*)(wlds + i) = s;
    }
    __syncthreads();

    const float* __restrict__ xb = x + (size_t)row * H;

    float acc = 0.f;
    #pragma unroll
    for (int j = 0; j < H / 256; ++j) {            // 8 iters
        const int off = j * 256 + lane * 4;
        const float4 xv = *(const float4*)(xb + off);
        const float4 wv = *(const float4*)(wlds + off);
        acc += xv.x * wv.x + xv.y * wv.y + xv.z * wv.z + xv.w * wv.w;
    }
    #pragma unroll
    for (int s = 32; s; s >>= 1) acc += __shfl_xor(acc, s, 64);
    if (lane == 0) xWy[row] = mask[row] ? NEG_INF : acc;
}

// Kernel 3: softmax over L per batch row. grid: B blocks x 256 threads (8 elems/thread).
__global__ __launch_bounds__(256) void k_softmax(
    const float* __restrict__ xWy, float* __restrict__ out)
{
    const int b    = blockIdx.x;
    const int tid  = threadIdx.x;
    const int wave = tid >> 6;
    const int lane = tid & 63;
    const float* __restrict__ v = xWy + (size_t)b * L;

    float vals[L / 256];
    float m = -INFINITY;
    #pragma unroll
    for (int j = 0; j < L / 256; ++j) {
        vals[j] = v[tid + j * 256];
        m = fmaxf(m, vals[j]);
    }
    #pragma unroll
    for (int s = 32; s; s >>= 1) m = fmaxf(m, __shfl_xor(m, s, 64));

    __shared__ float redm[4];
    if (lane == 0) redm[wave] = m;
    __syncthreads();
    m = fmaxf(fmaxf(redm[0], redm[1]), fmaxf(redm[2], redm[3]));

    float sum = 0.f;
    #pragma unroll
    for (int j = 0; j < L / 256; ++j) {
        vals[j] = __expf(vals[j] - m);
        sum += vals[j];
    }
    #pragma unroll
    for (int s = 32; s; s >>= 1) sum += __shfl_xor(sum, s, 64);

    __shared__ float reds[4];
    if (lane == 0) reds[wave] = sum;
    __syncthreads();
    sum = reds[0] + reds[1] + reds[2] + reds[3];

    const float inv = 1.0f / sum;
    #pragma unroll
    for (int j = 0; j < L / 256; ++j)
        out[(size_t)b * L + tid + j * 256] = vals[j] * inv;
}

extern "C" void kernel_launch(void* const* d_in, const int* in_sizes, int n_in,
                              void* d_out, int out_size, void* d_ws, size_t ws_size,
                              hipStream_t stream) {
    const float*         x       = (const float*)d_in[0];
    const float*         y       = (const float*)d_in[1];
    const unsigned char* mask    = (const unsigned char*)d_in[2];
    const int*           actions = (const int*)d_in[3];
    const float*         weight  = (const float*)d_in[4];
    const float*         bias    = (const float*)d_in[5];
    const float*         wa      = (const float*)d_in[6];
    const float*         ba      = (const float*)d_in[7];
    float*               out     = (float*)d_out;

    float* ws  = (float*)d_ws;
    float* Wyp = ws;                                // B*HSPLIT*H floats = 256 KB
    float* xWy = Wyp + (size_t)B * HSPLIT * H;      // B*L floats

    dim3 g1(XT, B / 2, HSPLIT);
    k_wy<<<g1, 256, 0, stream>>>(y, actions, weight, wa, bias, ba, Wyp);
    k_xwy<<<B * L / 8, 512, 0, stream>>>(x, Wyp, mask, xWy);
    k_softmax<<<B, 256, 0, stream>>>(xWy, out);
}